// Round 3
// baseline (65546.533 us; speedup 1.0000x reference)
//
#include <hip/hip_runtime.h>
#include <hip/hip_bf16.h>
#include <cstdint>

// Problem constants
#define V_ 100000
#define E_ 300
#define H_ 768
#define T_ 20
#define S_ 8192
#define EPAD 320          // 64 lanes * 5 k's (zero-padded past 300)
#define SENT 0xFFC0DEADu  // NaN bit pattern; real h is never NaN

// d_ws layout: float hb[(S_+1)][2][H_]  (slot t = h after t steps; slot 0 zeros,
// slots 1..S poisoned to SENT), then u32 flag (1 = inputs are fp32), u32 diag.

__device__ __forceinline__ float ldf(const void* p, int f32, size_t i) {
    return f32 ? ((const float*)p)[i]
               : __bfloat162float(((const __hip_bfloat16*)p)[i]);
}

__device__ __forceinline__ float sigf(float x) { return 1.0f / (1.0f + expf(-x)); }

__global__ void init_h_kernel(uint32_t* __restrict__ hb_u, int n,
                              const uint16_t* __restrict__ probe) {
    if (blockIdx.x == 0) {
        // Runtime dtype detection on b_ih_f (uniform +-0.036):
        // bf16 buffer: no element has exponent >= 0x81. fp32 buffer read as u16
        // halves: low halves ~uniform in exponent bits -> ~500/1024 hits.
        __shared__ int tot;
        if (threadIdx.x == 0) tot = 0;
        __syncthreads();
        int cnt = 0;
        for (int i = threadIdx.x; i < 2048; i += blockDim.x) {
            uint32_t e = (probe[i] >> 7) & 0xFF;
            cnt += (e >= 0x81) ? 1 : 0;
        }
        atomicAdd(&tot, cnt);
        __syncthreads();
        if (threadIdx.x == 0) {
            hb_u[n]     = (tot >= 32) ? 1u : 0u;  // 1 = fp32 inputs
            hb_u[n + 1] = 0u;                     // diag: sync-failure flag
        }
    }
    int stride = gridDim.x * blockDim.x;
    for (int i = blockIdx.x * blockDim.x + threadIdx.x; i < n; i += stride)
        hb_u[i] = (i < 2 * H_) ? 0u : SENT;
}

// 256 blocks x 448 threads (7 waves). Blocks 0..127: forward dir, 128..255: 'reverse'
// params (both scan forward in time, per reference). Wave 0 = sync wave (polls h(t),
// broadcasts via LDS). Waves 1..6 each own one h element (its 4 gate rows i,f,g,o)
// AND stage the embedding-row prefetch (so HBM latency never enters wave0's vmcnt FIFO).
__launch_bounds__(448, 1)
__global__ void lstm_scan_kernel(const int* __restrict__ idx,
                                 const void* __restrict__ emb,
                                 const void* __restrict__ Wih_f, const void* __restrict__ Whh_f,
                                 const void* __restrict__ bih_f, const void* __restrict__ bhh_f,
                                 const void* __restrict__ Wih_b, const void* __restrict__ Whh_b,
                                 const void* __restrict__ bih_b, const void* __restrict__ bhh_b,
                                 float* __restrict__ hb,
                                 const uint32_t* __restrict__ flagp,
                                 uint32_t* __restrict__ diag)
{
    __shared__ float hlds[2][H_];   // double-buffered previous-h broadcast (6 KB)
    __shared__ float xr[8][EPAD];   // embedding-row ring, prefetched 7 ahead (10.25 KB)

    const int f32  = (int)flagp[0];
    const int tid  = threadIdx.x;
    const int wave = tid >> 6;
    const int lane = tid & 63;
    const int blk  = blockIdx.x;
    const int dir  = blk >> 7;

    const void* Wih = dir ? Wih_b : Wih_f;
    const void* Whh = dir ? Whh_b : Whh_f;
    const void* bih = dir ? bih_b : bih_f;
    const void* bhh = dir ? bhh_b : bhh_f;

    // zero the x-ring pad columns [300,320) once
    for (int i = tid; i < 8 * (EPAD - E_); i += blockDim.x) {
        int s = i / (EPAD - E_), k = E_ + i % (EPAD - E_);
        xr[s][k] = 0.0f;
    }

    // Per-lane resident weights (fp32 in VGPRs): recurrent k-chunk 12/lane, input 5/lane
    float whh[4][12];
    float wih[4][5];
    float bias[4];
    int e = 0;
    if (wave > 0) {
        e = (blk & 127) * 6 + (wave - 1);
        #pragma unroll
        for (int g = 0; g < 4; ++g) {
            int row = g * H_ + e;  // PyTorch gate order i,f,g,o stacked on 4H
            #pragma unroll
            for (int j = 0; j < 12; ++j)
                whh[g][j] = ldf(Whh, f32, (size_t)row * H_ + 12 * lane + j);
            #pragma unroll
            for (int j = 0; j < 5; ++j) {
                int k = 5 * lane + j;
                wih[g][j] = (k < E_) ? ldf(Wih, f32, (size_t)row * E_ + k) : 0.0f;
            }
            bias[g] = ldf(bih, f32, row) + ldf(bhh, f32, row);
        }
        // Prefill x ring slots 0..6 (waves 1..6 cover 384 >= 300 indices)
        int xi = (wave - 1) * 64 + lane;
        for (int d = 0; d < 7; ++d)
            if (xi < E_) xr[d][xi] = ldf(emb, f32, (size_t)idx[d] * E_ + xi);
    }
    __syncthreads();

    const uint32_t* hb_u = (const uint32_t*)hb;
    uint32_t*       hb_w = (uint32_t*)hb;
    float c = 0.0f;
    int fuel = 4000000;  // safety: converts a would-be deadlock into a finite run

    for (int t = 0; t < S_; ++t) {
        float xv = 0.0f;
        int   xi = -1;

        if (wave == 0) {
            // poll h(t): lane owns k = 12*lane .. +12. Only poll loads live in this
            // wave's vmcnt FIFO; s_sleep backoff cuts fabric contention.
            size_t hbase = ((size_t)t * 2 + dir) * H_ + 12 * lane;
            uint32_t v[12];
            for (;;) {
                bool ok = true;
                #pragma unroll
                for (int j = 0; j < 12; ++j) {
                    v[j] = __hip_atomic_load(hb_u + hbase + j, __ATOMIC_RELAXED,
                                             __HIP_MEMORY_SCOPE_AGENT);
                    ok &= (v[j] != SENT);
                }
                if (__all(ok)) break;
                if (--fuel < 0) break;
                __builtin_amdgcn_s_sleep(1);
            }
            if (fuel < 0) {  // sync failure: flag it, substitute finite marker
                if (lane == 0) atomicOr(diag, 1u);
                #pragma unroll
                for (int j = 0; j < 12; ++j)
                    if (v[j] == SENT) v[j] = __float_as_uint(1000.0f);
            }
            float* dst = hlds[t & 1];
            #pragma unroll
            for (int j = 0; j < 12; ++j) dst[12 * lane + j] = __uint_as_float(v[j]);
        } else {
            // issue emb-row(t+7) prefetch; drains in parallel with wave0's poll
            if (t + 7 < S_) {
                xi = (wave - 1) * 64 + lane;
                if (xi < E_) xv = ldf(emb, f32, (size_t)idx[t + 7] * E_ + xi);
                else xi = -1;
            }
        }

        __syncthreads();  // uniform: every wave hits exactly one per iteration

        if (wave > 0) {
            const float* hsrc = hlds[t & 1];
            float hloc[12], xloc[5];
            #pragma unroll
            for (int j = 0; j < 12; ++j) hloc[j] = hsrc[12 * lane + j];
            const float* xs = xr[t & 7];
            #pragma unroll
            for (int j = 0; j < 5; ++j) xloc[j] = xs[5 * lane + j];

            float acc[4];
            #pragma unroll
            for (int g = 0; g < 4; ++g) {
                float s = 0.0f;
                #pragma unroll
                for (int j = 0; j < 12; ++j) s = fmaf(whh[g][j], hloc[j], s);
                #pragma unroll
                for (int j = 0; j < 5; ++j)  s = fmaf(wih[g][j], xloc[j], s);
                acc[g] = s;
            }
            // butterfly all-reduce of the 4 gate partials across the 64-lane wave
            #pragma unroll
            for (int m = 1; m < 64; m <<= 1) {
                #pragma unroll
                for (int g = 0; g < 4; ++g) acc[g] += __shfl_xor(acc[g], m, 64);
            }
            float gi = sigf(acc[0] + bias[0]);
            float gf = sigf(acc[1] + bias[1]);
            float gg = tanhf(acc[2] + bias[2]);
            float go = sigf(acc[3] + bias[3]);
            c = gf * c + gi * gg;
            float hv = go * tanhf(c);
            if (lane == 0) {
                size_t o = ((size_t)(t + 1) * 2 + dir) * H_ + e;
                __hip_atomic_store(hb_w + o, __float_as_uint(hv), __ATOMIC_RELAXED,
                                   __HIP_MEMORY_SCOPE_AGENT);
            }
            // land the prefetched emb row in ring slot (t+7)&7; its readers run at
            // step t+7, separated by 7 barriers — no collision with slot t&7 readers
            if (xi >= 0) xr[(t + 7) & 7][xi] = xv;
        }
    }
}

// out[k] = b_tag[k] + sum_j W_tag[k][j] * hcat[j], hcat = hb[S] = [hf(768); hb(768)]
__global__ void tag_kernel(const void* __restrict__ Wtag,
                           const void* __restrict__ btag,
                           const float* __restrict__ hb,
                           void* __restrict__ out,
                           const uint32_t* __restrict__ flagp,
                           const uint32_t* __restrict__ diag)
{
    const int f32 = (int)flagp[0];
    const float pen = (diag[0] != 0) ? 1.0e6f : 0.0f;  // make sync failure unmistakable
    int wave = threadIdx.x >> 6, lane = threadIdx.x & 63;
    const float* hcat = hb + (size_t)S_ * 2 * H_;  // 1536 floats, [hf; hb]
    for (int k = wave; k < T_; k += 10) {
        float s = 0.0f;
        #pragma unroll
        for (int j = 0; j < 24; ++j)
            s = fmaf(ldf(Wtag, f32, (size_t)k * 2 * H_ + 24 * lane + j),
                     hcat[24 * lane + j], s);
        #pragma unroll
        for (int m = 1; m < 64; m <<= 1) s += __shfl_xor(s, m, 64);
        if (lane == 0) {
            float v = s + ldf(btag, f32, k) + pen;
            if (f32) ((float*)out)[k] = v;
            else     ((__hip_bfloat16*)out)[k] = __float2bfloat16(v);
        }
    }
}

extern "C" void kernel_launch(void* const* d_in, const int* in_sizes, int n_in,
                              void* d_out, int out_size, void* d_ws, size_t ws_size,
                              hipStream_t stream)
{
    const int* idx = (const int*)d_in[0];
    const void* emb   = d_in[1];
    const void* Wih_f = d_in[2];
    const void* Whh_f = d_in[3];
    const void* bih_f = d_in[4];
    const void* bhh_f = d_in[5];
    const void* Wih_b = d_in[6];
    const void* Whh_b = d_in[7];
    const void* bih_b = d_in[8];
    const void* bhh_b = d_in[9];
    const void* Wtag  = d_in[10];
    const void* btag  = d_in[11];

    float* hb = (float*)d_ws;          // (S+1)*2*H*4 = 50,337,792 bytes
    int n = (S_ + 1) * 2 * H_;
    uint32_t* flagp = (uint32_t*)d_ws + n;      // [n] = f32 flag, [n+1] = diag
    uint32_t* diag  = flagp + 1;

    init_h_kernel<<<dim3(4096), dim3(256), 0, stream>>>(
        (uint32_t*)hb, n, (const uint16_t*)bih_f);
    lstm_scan_kernel<<<dim3(256), dim3(448), 0, stream>>>(
        idx, emb, Wih_f, Whh_f, bih_f, bhh_f, Wih_b, Whh_b, bih_b, bhh_b,
        hb, flagp, diag);
    tag_kernel<<<dim3(1), dim3(640), 0, stream>>>(
        Wtag, btag, hb, d_out, flagp, diag);
}

// Round 4
// 42764.282 us; speedup vs baseline: 1.5327x; 1.5327x over previous
//
#include <hip/hip_runtime.h>
#include <hip/hip_bf16.h>
#include <cstdint>

// Problem constants
#define V_ 100000
#define E_ 300
#define H_ 768
#define T_ 20
#define S_ 8192
#define EPAD 320          // 64 lanes * 5 k's (zero-padded past 300)
#define SENT 0xFFC0DEADu  // NaN bit pattern; real h is never NaN

// d_ws layout: float hb[(S_+1)][2][H_]  (slot t = h after t steps; slot 0 zeros,
// slots 1..S poisoned to SENT), then u32 flag (1 = inputs are fp32), u32 diag.

__device__ __forceinline__ float ldf(const void* p, int f32, size_t i) {
    return f32 ? ((const float*)p)[i]
               : __bfloat162float(((const __hip_bfloat16*)p)[i]);
}

__device__ __forceinline__ float sigf(float x) { return 1.0f / (1.0f + expf(-x)); }

__global__ void init_h_kernel(uint32_t* __restrict__ hb_u, int n,
                              const uint16_t* __restrict__ probe) {
    if (blockIdx.x == 0) {
        // Runtime dtype detection on b_ih_f (uniform +-0.036): bf16 buffer has no
        // element with exponent >= 0x81; fp32 buffer read as u16 halves: ~50% hits.
        __shared__ int tot;
        if (threadIdx.x == 0) tot = 0;
        __syncthreads();
        int cnt = 0;
        for (int i = threadIdx.x; i < 2048; i += blockDim.x) {
            uint32_t e = (probe[i] >> 7) & 0xFF;
            cnt += (e >= 0x81) ? 1 : 0;
        }
        atomicAdd(&tot, cnt);
        __syncthreads();
        if (threadIdx.x == 0) {
            hb_u[n]     = (tot >= 32) ? 1u : 0u;  // 1 = fp32 inputs
            hb_u[n + 1] = 0u;                     // diag: sync-failure flag
        }
    }
    int stride = gridDim.x * blockDim.x;
    for (int i = blockIdx.x * blockDim.x + threadIdx.x; i < n; i += stride)
        hb_u[i] = (i < 2 * H_) ? 0u : SENT;
}

// Vectorized MALL-coherent poll read: 48 B at p (16B-aligned), bypassing L1/L2.
__device__ __forceinline__ void poll48(const uint32_t* p, uint4& a, uint4& b, uint4& c) {
    asm volatile(
        "global_load_dwordx4 %0, %3, off sc0 sc1\n\t"
        "global_load_dwordx4 %1, %3, off offset:16 sc0 sc1\n\t"
        "global_load_dwordx4 %2, %3, off offset:32 sc0 sc1\n\t"
        "s_waitcnt vmcnt(0)"
        : "=&v"(a), "=&v"(b), "=&v"(c)
        : "v"(p)
        : "memory");
}

// 256 blocks x 512 threads (8 waves). Blocks 0..127: forward dir, 128..255: 'reverse'
// params (both scan forward in time, per reference).
//   wave 0   : sync wave — polls h(t) from the MALL, broadcasts via LDS
//   waves 1-6: compute — each owns one h element (4 gate rows i,f,g,o); pure LDS+VALU
//   wave 7   : emb prefetch — reg-double-buffered so its HBM loads get a full step
//              to drain and never sit in anyone's barrier vmcnt drain
__launch_bounds__(512, 1)
__global__ void lstm_scan_kernel(const int* __restrict__ idx,
                                 const void* __restrict__ emb,
                                 const void* __restrict__ Wih_f, const void* __restrict__ Whh_f,
                                 const void* __restrict__ bih_f, const void* __restrict__ bhh_f,
                                 const void* __restrict__ Wih_b, const void* __restrict__ Whh_b,
                                 const void* __restrict__ bih_b, const void* __restrict__ bhh_b,
                                 float* __restrict__ hb,
                                 const uint32_t* __restrict__ flagp,
                                 uint32_t* __restrict__ diag)
{
    __shared__ float hlds[2][H_];   // double-buffered previous-h broadcast (6 KB)
    __shared__ float xr[8][EPAD];   // embedding-row ring (10.25 KB)

    const int f32  = (int)flagp[0];
    const int tid  = threadIdx.x;
    const int wave = tid >> 6;
    const int lane = tid & 63;
    const int blk  = blockIdx.x;
    const int dir  = blk >> 7;

    const void* Wih = dir ? Wih_b : Wih_f;
    const void* Whh = dir ? Whh_b : Whh_f;
    const void* bih = dir ? bih_b : bih_f;
    const void* bhh = dir ? bhh_b : bhh_f;

    // zero the x-ring pad columns [300,320) once
    for (int i = tid; i < 8 * (EPAD - E_); i += blockDim.x) {
        int s = i / (EPAD - E_), k = E_ + i % (EPAD - E_);
        xr[s][k] = 0.0f;
    }

    // Per-lane resident weights (fp32 in VGPRs): recurrent k-chunk 12/lane, input 5/lane
    float whh[4][12];
    float wih[4][5];
    float bias[4];
    int e = 0;
    if (wave >= 1 && wave <= 6) {
        e = (blk & 127) * 6 + (wave - 1);
        #pragma unroll
        for (int g = 0; g < 4; ++g) {
            int row = g * H_ + e;  // PyTorch gate order i,f,g,o stacked on 4H
            #pragma unroll
            for (int j = 0; j < 12; ++j)
                whh[g][j] = ldf(Whh, f32, (size_t)row * H_ + 12 * lane + j);
            #pragma unroll
            for (int j = 0; j < 5; ++j) {
                int k = 5 * lane + j;
                wih[g][j] = (k < E_) ? ldf(Wih, f32, (size_t)row * E_ + k) : 0.0f;
            }
            bias[g] = ldf(bih, f32, row) + ldf(bhh, f32, row);
        }
    }

    // Prefetch wave: prefill ring slots 0..5 (rows 0..5) and preload row 6 into regs
    float xn[5];
    if (wave == 7) {
        for (int d = 0; d < 6; ++d) {
            size_t base = (size_t)idx[d] * E_;
            for (int i = lane; i < E_; i += 64)
                xr[d][i] = ldf(emb, f32, base + i);
        }
        size_t base6 = (size_t)idx[6] * E_;
        #pragma unroll
        for (int r = 0; r < 5; ++r) {
            int i = lane + 64 * r;
            xn[r] = (i < E_) ? ldf(emb, f32, base6 + i) : 0.0f;
        }
    }
    __syncthreads();

    const uint32_t* hb_u = (const uint32_t*)hb;
    uint32_t*       hb_w = (uint32_t*)hb;
    float c = 0.0f;
    int fuel = 4000000;  // safety: converts a would-be deadlock into a finite run

    for (int t = 0; t < S_; ++t) {
        if (wave == 0) {
            // poll h(t): lane owns dwords [12*lane, 12*lane+12) of this dir's h
            size_t hbase = ((size_t)t * 2 + dir) * H_ + 12 * lane;
            const uint32_t* p = hb_u + hbase;
            uint4 a, b, cc;
            for (;;) {
                poll48(p, a, b, cc);
                bool ok = (a.x != SENT) & (a.y != SENT) & (a.z != SENT) & (a.w != SENT) &
                          (b.x != SENT) & (b.y != SENT) & (b.z != SENT) & (b.w != SENT) &
                          (cc.x != SENT) & (cc.y != SENT) & (cc.z != SENT) & (cc.w != SENT);
                if (__all(ok)) break;
                if (--fuel < 0) break;
                __builtin_amdgcn_s_sleep(1);
            }
            uint32_t v[12] = {a.x, a.y, a.z, a.w, b.x, b.y, b.z, b.w, cc.x, cc.y, cc.z, cc.w};
            if (fuel < 0) {  // sync failure: flag it, substitute finite marker
                if (lane == 0) atomicOr(diag, 1u);
                #pragma unroll
                for (int j = 0; j < 12; ++j)
                    if (v[j] == SENT) v[j] = __float_as_uint(1000.0f);
            }
            float* dst = hlds[t & 1];
            #pragma unroll
            for (int j = 0; j < 12; ++j) dst[12 * lane + j] = __uint_as_float(v[j]);
        } else if (wave == 7) {
            // land row t+6 (loaded LAST iteration — already drained, zero wait)
            // into slot (t+6)&7; its readers run at step t+6 (>= 5 barriers away)
            if (t + 6 < S_) {
                float* xd = xr[(t + 6) & 7];
                #pragma unroll
                for (int r = 0; r < 5; ++r) {
                    int i = lane + 64 * r;
                    if (i < E_) xd[i] = xn[r];
                }
            }
            // issue row t+7 loads; they drain during this + next step's poll
            if (t + 7 < S_) {
                size_t base = (size_t)idx[t + 7] * E_;
                #pragma unroll
                for (int r = 0; r < 5; ++r) {
                    int i = lane + 64 * r;
                    xn[r] = (i < E_) ? ldf(emb, f32, base + i) : 0.0f;
                }
            }
        }

        __syncthreads();  // uniform: every wave hits exactly one per iteration

        if (wave >= 1 && wave <= 6) {
            const float* hsrc = hlds[t & 1];
            float hloc[12], xloc[5];
            #pragma unroll
            for (int j = 0; j < 12; ++j) hloc[j] = hsrc[12 * lane + j];
            const float* xs = xr[t & 7];
            #pragma unroll
            for (int j = 0; j < 5; ++j) xloc[j] = xs[5 * lane + j];

            float acc[4];
            #pragma unroll
            for (int g = 0; g < 4; ++g) {
                float s = 0.0f;
                #pragma unroll
                for (int j = 0; j < 12; ++j) s = fmaf(whh[g][j], hloc[j], s);
                #pragma unroll
                for (int j = 0; j < 5; ++j)  s = fmaf(wih[g][j], xloc[j], s);
                acc[g] = s;
            }
            // butterfly all-reduce of the 4 gate partials across the 64-lane wave
            #pragma unroll
            for (int m = 1; m < 64; m <<= 1) {
                #pragma unroll
                for (int g = 0; g < 4; ++g) acc[g] += __shfl_xor(acc[g], m, 64);
            }
            float gi = sigf(acc[0] + bias[0]);
            float gf = sigf(acc[1] + bias[1]);
            float gg = tanhf(acc[2] + bias[2]);
            float go = sigf(acc[3] + bias[3]);
            c = gf * c + gi * gg;
            float hv = go * tanhf(c);
            if (lane == 0) {
                size_t o = ((size_t)(t + 1) * 2 + dir) * H_ + e;
                __hip_atomic_store(hb_w + o, __float_as_uint(hv), __ATOMIC_RELAXED,
                                   __HIP_MEMORY_SCOPE_AGENT);
            }
        }
    }
}

// out[k] = b_tag[k] + sum_j W_tag[k][j] * hcat[j], hcat = hb[S] = [hf(768); hb(768)]
__global__ void tag_kernel(const void* __restrict__ Wtag,
                           const void* __restrict__ btag,
                           const float* __restrict__ hb,
                           void* __restrict__ out,
                           const uint32_t* __restrict__ flagp,
                           const uint32_t* __restrict__ diag)
{
    const int f32 = (int)flagp[0];
    const float pen = (diag[0] != 0) ? 1.0e6f : 0.0f;  // make sync failure unmistakable
    int wave = threadIdx.x >> 6, lane = threadIdx.x & 63;
    const float* hcat = hb + (size_t)S_ * 2 * H_;  // 1536 floats, [hf; hb]
    for (int k = wave; k < T_; k += 10) {
        float s = 0.0f;
        #pragma unroll
        for (int j = 0; j < 24; ++j)
            s = fmaf(ldf(Wtag, f32, (size_t)k * 2 * H_ + 24 * lane + j),
                     hcat[24 * lane + j], s);
        #pragma unroll
        for (int m = 1; m < 64; m <<= 1) s += __shfl_xor(s, m, 64);
        if (lane == 0) {
            float v = s + ldf(btag, f32, k) + pen;
            if (f32) ((float*)out)[k] = v;
            else     ((__hip_bfloat16*)out)[k] = __float2bfloat16(v);
        }
    }
}

extern "C" void kernel_launch(void* const* d_in, const int* in_sizes, int n_in,
                              void* d_out, int out_size, void* d_ws, size_t ws_size,
                              hipStream_t stream)
{
    const int* idx = (const int*)d_in[0];
    const void* emb   = d_in[1];
    const void* Wih_f = d_in[2];
    const void* Whh_f = d_in[3];
    const void* bih_f = d_in[4];
    const void* bhh_f = d_in[5];
    const void* Wih_b = d_in[6];
    const void* Whh_b = d_in[7];
    const void* bih_b = d_in[8];
    const void* bhh_b = d_in[9];
    const void* Wtag  = d_in[10];
    const void* btag  = d_in[11];

    float* hb = (float*)d_ws;          // (S+1)*2*H*4 = 50,337,792 bytes
    int n = (S_ + 1) * 2 * H_;
    uint32_t* flagp = (uint32_t*)d_ws + n;      // [n] = f32 flag, [n+1] = diag
    uint32_t* diag  = flagp + 1;

    init_h_kernel<<<dim3(4096), dim3(256), 0, stream>>>(
        (uint32_t*)hb, n, (const uint16_t*)bih_f);
    lstm_scan_kernel<<<dim3(256), dim3(512), 0, stream>>>(
        idx, emb, Wih_f, Whh_f, bih_f, bhh_f, Wih_b, Whh_b, bih_b, bhh_b,
        hb, flagp, diag);
    tag_kernel<<<dim3(1), dim3(640), 0, stream>>>(
        Wtag, btag, hb, d_out, flagp, diag);
}